// Round 2
// baseline (1999.728 us; speedup 1.0000x reference)
//
#include <hip/hip_runtime.h>

// LinformerSelfAttention  B=4 N=4096 E=1024 H=16 D=64 K=256 RANK=32
// All inputs/outputs are FLOAT32 (per reference dtypes).
// Workspace (f32): t1 M*32 | t2 M*512 | q M*1024 (attn output in-place) |
//                  km M*64 | kv 4*256*64   -> ~102 MB total.

__device__ __forceinline__ void load4f(const float* p, float* o) {
    float4 v = *reinterpret_cast<const float4*>(p);
    o[0] = v.x; o[1] = v.y; o[2] = v.z; o[3] = v.w;
}

// C[m,n] = sum_k A[m,k]*B[n,k] (+ bias[n]).  Tile 64x64, BK=16, 256 thr,
// 4x4 microtile per thread. M % 64 == 0; N arbitrary (ragged guarded).
template <bool HAS_BIAS>
__global__ __launch_bounds__(256)
void gemm_bt(const float* __restrict__ A, const float* __restrict__ B,
             const float* __restrict__ bias, float* __restrict__ C,
             int M, int N, int K) {
    const int BM = 64, BN = 64, BK = 16;
    __shared__ float As[BK][BM + 1];
    __shared__ float Bs[BK][BN + 1];
    const int tid = threadIdx.x;
    const int tx = tid & 15, ty = tid >> 4;
    const int m0 = blockIdx.y * BM, n0 = blockIdx.x * BN;
    const int arow = tid >> 2;        // 0..63
    const int acol = (tid & 3) * 4;   // 0,4,8,12

    float c[4][4] = {};

    for (int k0 = 0; k0 < K; k0 += BK) {
        float av[4];
        load4f(&A[(size_t)(m0 + arow) * K + k0 + acol], av);
        As[acol + 0][arow] = av[0];
        As[acol + 1][arow] = av[1];
        As[acol + 2][arow] = av[2];
        As[acol + 3][arow] = av[3];

        float bv[4] = {0.f, 0.f, 0.f, 0.f};
        if (n0 + arow < N) load4f(&B[(size_t)(n0 + arow) * K + k0 + acol], bv);
        Bs[acol + 0][arow] = bv[0];
        Bs[acol + 1][arow] = bv[1];
        Bs[acol + 2][arow] = bv[2];
        Bs[acol + 3][arow] = bv[3];

        __syncthreads();
#pragma unroll
        for (int kk = 0; kk < BK; ++kk) {
            float a[4], b[4];
#pragma unroll
            for (int i = 0; i < 4; ++i) a[i] = As[kk][ty * 4 + i];
#pragma unroll
            for (int j = 0; j < 4; ++j) b[j] = Bs[kk][tx * 4 + j];
#pragma unroll
            for (int i = 0; i < 4; ++i)
#pragma unroll
                for (int j = 0; j < 4; ++j) c[i][j] += a[i] * b[j];
        }
        __syncthreads();
    }

#pragma unroll
    for (int i = 0; i < 4; ++i) {
        const int m = m0 + ty * 4 + i;
#pragma unroll
        for (int j = 0; j < 4; ++j) {
            const int n = n0 + tx * 4 + j;
            if (n < N) {
                float v = c[i][j];
                if (HAS_BIAS) v += bias[n];
                C[(size_t)m * N + n] = v;
            }
        }
    }
}

// kv[b,kc,d] = sum_n kmat[b,n,d] * key_proj[n,kc].  grid (16,4), 256 thr.
__global__ __launch_bounds__(256)
void kv_kernel(const float* __restrict__ kmat, const float* __restrict__ kp,
               float* __restrict__ kv) {
    const int b = blockIdx.y;
    const int kk0 = blockIdx.x * 16;
    const int tid = threadIdx.x;
    const int d = tid & 63, s = tid >> 6;

    float acc[16] = {};
    for (int n = s; n < 4096; n += 4) {
        const float kval = kmat[((size_t)b * 4096 + n) * 64 + d];
        const float* kpr = &kp[(size_t)n * 256 + kk0];
#pragma unroll
        for (int j = 0; j < 16; ++j) acc[j] += kval * kpr[j];
    }

    __shared__ float sm[16][4][64];
#pragma unroll
    for (int j = 0; j < 16; ++j) sm[j][s][d] = acc[j];
    __syncthreads();

    for (int o = tid; o < 16 * 64; o += 256) {
        const int j = o >> 6, dd = o & 63;
        kv[((size_t)b * 256 + kk0 + j) * 64 + dd] =
            sm[j][0][dd] + sm[j][1][dd] + sm[j][2][dd] + sm[j][3][dd];
    }
}

// One thread per query (b,h,n): online softmax over 256 keys, D=64.
// attn may alias q: each thread reads only its own 64-elem slice into
// registers before writing the same slice (no __restrict__ here).
__global__ __launch_bounds__(64)
void attn_kernel(const float* q, const float* __restrict__ kv, float* attn) {
    const int n = blockIdx.x * 64 + threadIdx.x;
    const int h = blockIdx.y;
    const int b = blockIdx.z;
    const float* qp = q + ((size_t)(b * 4096 + n)) * 1024 + h * 64;
    const float* kvb = kv + (size_t)b * 256 * 64;

    float qv[64];
#pragma unroll
    for (int i = 0; i < 16; ++i) load4f(qp + i * 4, qv + i * 4);

    float m = -1e30f, l = 0.f;
    float acc[64];
#pragma unroll
    for (int d = 0; d < 64; ++d) acc[d] = 0.f;

    for (int k = 0; k < 256; ++k) {
        const float* kr = kvb + k * 64;
        float s = 0.f;
#pragma unroll
        for (int d = 0; d < 64; ++d) s += qv[d] * kr[d];
        s *= 0.125f;  // D^-0.5
        if (s <= m) {
            const float p = __expf(s - m);
            l += p;
#pragma unroll
            for (int d = 0; d < 64; ++d) acc[d] += p * kr[d];
        } else {
            const float corr = __expf(m - s);
            m = s;
            l = l * corr + 1.f;
#pragma unroll
            for (int d = 0; d < 64; ++d) acc[d] = acc[d] * corr + kr[d];
        }
    }

    const float inv = 1.f / l;
    float* op = attn + ((size_t)(b * 4096 + n)) * 1024 + h * 64;
#pragma unroll
    for (int d = 0; d < 64; ++d) op[d] = acc[d] * inv;
}

extern "C" void kernel_launch(void* const* d_in, const int* in_sizes, int n_in,
                              void* d_out, int out_size, void* d_ws, size_t ws_size,
                              hipStream_t stream) {
    const float* x  = (const float*)d_in[0];
    const float* qU = (const float*)d_in[1];
    const float* qV = (const float*)d_in[2];
    const float* qW = (const float*)d_in[3];
    const float* qb = (const float*)d_in[4];
    const float* kW = (const float*)d_in[5];
    const float* kp = (const float*)d_in[6];
    const float* oW = (const float*)d_in[7];
    const float* ob = (const float*)d_in[8];
    float* out = (float*)d_out;

    const int M = 4 * 4096;  // 16384 rows
    float* ws = (float*)d_ws;
    float* t1 = ws;                                // M*32      (2 MB)
    float* t2 = t1 + (size_t)M * 32;               // M*512     (32 MB)
    float* q  = t2 + (size_t)M * 512;              // M*1024    (64 MB)
    float* km = q  + (size_t)M * 1024;             // M*64      (4 MB)
    float* kv = km + (size_t)M * 64;               // 4*256*64  (256 KB)
    float* at = q;                                 // attention output in-place

    const dim3 blk(256);
    // 1) t1 = x @ qU^T           (M,32,K=1024)
    gemm_bt<false><<<dim3(1, M / 64), blk, 0, stream>>>(x, qU, nullptr, t1, M, 32, 1024);
    // 2) t2 = t1 @ qV^T          (M,512,K=32)
    gemm_bt<false><<<dim3(8, M / 64), blk, 0, stream>>>(t1, qV, nullptr, t2, M, 512, 32);
    // 3) q = t2 @ qW^T + qb      (M,1024,K=512)
    gemm_bt<true><<<dim3(16, M / 64), blk, 0, stream>>>(t2, qW, qb, q, M, 1024, 512);
    // 4) k = x @ kW^T            (M,64,K=1024)
    gemm_bt<false><<<dim3(1, M / 64), blk, 0, stream>>>(x, kW, nullptr, km, M, 64, 1024);
    // 5) kv = key_proj^T-reduce over n
    kv_kernel<<<dim3(16, 4), blk, 0, stream>>>(km, kp, kv);
    // 6) attention (online softmax, K=256, D=64), in-place on q
    attn_kernel<<<dim3(64, 16, 4), dim3(64), 0, stream>>>(q, kv, at);
    // 7) out = attn @ oW^T + ob  (M,1024,K=1024)
    gemm_bt<true><<<dim3(16, M / 64), blk, 0, stream>>>(at, oW, ob, out, M, 1024, 1024);
}

// Round 3
// 864.988 us; speedup vs baseline: 2.3119x; 2.3119x over previous
//
#include <hip/hip_runtime.h>
#include <hip/hip_bf16.h>

// LinformerSelfAttention  B=4 N=4096 E=1024 H=16 D=64 K=256 RANK=32
// f32 I/O. Big GEMMs via split-bf16 MFMA (hi/lo, 3 products -> f32-grade).

typedef unsigned short u16;
typedef __attribute__((ext_vector_type(8))) short bf8;    // 8 bf16, 4 VGPRs
typedef __attribute__((ext_vector_type(4))) float f32x4;

__device__ __forceinline__ u16 f2bf(float x) {
    __hip_bfloat16 h = __float2bfloat16(x);
    return *reinterpret_cast<u16*>(&h);
}
__device__ __forceinline__ float bf2f16(u16 u) {
    unsigned int v = ((unsigned int)u) << 16;
    union { unsigned int i; float f; } c; c.i = v; return c.f;
}
__device__ __forceinline__ void load4f(const float* p, float* o) {
    float4 v = *reinterpret_cast<const float4*>(p);
    o[0] = v.x; o[1] = v.y; o[2] = v.z; o[3] = v.w;
}

// ---------------- MFMA split-bf16 GEMM ----------------
// C[m,n] = sum_k A[m,k]*B[n,k] (+bias[n]).  M%128==0, N%128==0, K%32==0.
// BM=BN=128, BK=32. 256 threads = 4 waves in 2x2. Each wave: 4x4 of 16x16.
template <bool HAS_BIAS>
__global__ __launch_bounds__(256)
void gemm_bt_mfma(const float* __restrict__ A, const float* __restrict__ B,
                  const float* __restrict__ bias, float* __restrict__ C,
                  int M, int N, int K) {
    __shared__ u16 Ah[128][40], Al[128][40], Bh[128][40], Bl[128][40];
    const int t = threadIdx.x;
    const int m0 = blockIdx.y * 128, n0 = blockIdx.x * 128;
    const int wave = t >> 6, lane = t & 63;
    const int wm = (wave >> 1) * 64, wn = (wave & 1) * 64;
    const int l15 = lane & 15, quad = lane >> 4;

    f32x4 acc[4][4] = {};

    const int srow = t >> 3;        // 0..31
    const int scol = (t & 7) * 4;   // 0,4,..,28

    for (int k0 = 0; k0 < K; k0 += 32) {
#pragma unroll
        for (int rr = 0; rr < 128; rr += 32) {
            const int row = rr + srow;
            float av[4], bv[4];
            load4f(&A[(size_t)(m0 + row) * K + k0 + scol], av);
            load4f(&B[(size_t)(n0 + row) * K + k0 + scol], bv);
            ushort4 ah, al, bh, bl;
            u16* ahp = (u16*)&ah; u16* alp = (u16*)&al;
            u16* bhp = (u16*)&bh; u16* blp = (u16*)&bl;
#pragma unroll
            for (int i = 0; i < 4; ++i) {
                u16 h = f2bf(av[i]); ahp[i] = h; alp[i] = f2bf(av[i] - bf2f16(h));
                u16 g = f2bf(bv[i]); bhp[i] = g; blp[i] = f2bf(bv[i] - bf2f16(g));
            }
            *reinterpret_cast<ushort4*>(&Ah[row][scol]) = ah;
            *reinterpret_cast<ushort4*>(&Al[row][scol]) = al;
            *reinterpret_cast<ushort4*>(&Bh[row][scol]) = bh;
            *reinterpret_cast<ushort4*>(&Bl[row][scol]) = bl;
        }
        __syncthreads();

        bf8 ahf[4], alf[4], bhf[4], blf[4];
#pragma unroll
        for (int i = 0; i < 4; ++i) {
            ahf[i] = *reinterpret_cast<const bf8*>(&Ah[wm + i * 16 + l15][quad * 8]);
            alf[i] = *reinterpret_cast<const bf8*>(&Al[wm + i * 16 + l15][quad * 8]);
            bhf[i] = *reinterpret_cast<const bf8*>(&Bh[wn + i * 16 + l15][quad * 8]);
            blf[i] = *reinterpret_cast<const bf8*>(&Bl[wn + i * 16 + l15][quad * 8]);
        }
#pragma unroll
        for (int i = 0; i < 4; ++i)
#pragma unroll
            for (int j = 0; j < 4; ++j) {
                acc[i][j] = __builtin_amdgcn_mfma_f32_16x16x32_bf16(ahf[i], bhf[j], acc[i][j], 0, 0, 0);
                acc[i][j] = __builtin_amdgcn_mfma_f32_16x16x32_bf16(ahf[i], blf[j], acc[i][j], 0, 0, 0);
                acc[i][j] = __builtin_amdgcn_mfma_f32_16x16x32_bf16(alf[i], bhf[j], acc[i][j], 0, 0, 0);
            }
        __syncthreads();
    }

    // C/D layout (m89): col = lane&15, row = quad*4 + reg
#pragma unroll
    for (int j = 0; j < 4; ++j) {
        const int col = n0 + wn + j * 16 + l15;
        const float badd = HAS_BIAS ? bias[col] : 0.f;
#pragma unroll
        for (int i = 0; i < 4; ++i) {
            const int rbase = m0 + wm + i * 16 + quad * 4;
#pragma unroll
            for (int r = 0; r < 4; ++r)
                C[(size_t)(rbase + r) * N + col] = acc[i][j][r] + badd;
        }
    }
}

// ---------------- small-N VALU GEMM (steps 1,4) ----------------
template <bool HAS_BIAS>
__global__ __launch_bounds__(256)
void gemm_bt(const float* __restrict__ A, const float* __restrict__ B,
             const float* __restrict__ bias, float* __restrict__ C,
             int M, int N, int K) {
    const int BM = 64, BN = 64, BK = 16;
    __shared__ float As[BK][BM + 1];
    __shared__ float Bs[BK][BN + 1];
    const int tid = threadIdx.x;
    const int tx = tid & 15, ty = tid >> 4;
    const int m0 = blockIdx.y * BM, n0 = blockIdx.x * BN;
    const int arow = tid >> 2;
    const int acol = (tid & 3) * 4;

    float c[4][4] = {};

    for (int k0 = 0; k0 < K; k0 += BK) {
        float av[4];
        load4f(&A[(size_t)(m0 + arow) * K + k0 + acol], av);
        As[acol + 0][arow] = av[0];
        As[acol + 1][arow] = av[1];
        As[acol + 2][arow] = av[2];
        As[acol + 3][arow] = av[3];

        float bv[4] = {0.f, 0.f, 0.f, 0.f};
        if (n0 + arow < N) load4f(&B[(size_t)(n0 + arow) * K + k0 + acol], bv);
        Bs[acol + 0][arow] = bv[0];
        Bs[acol + 1][arow] = bv[1];
        Bs[acol + 2][arow] = bv[2];
        Bs[acol + 3][arow] = bv[3];

        __syncthreads();
#pragma unroll
        for (int kk = 0; kk < BK; ++kk) {
            float a[4], b[4];
#pragma unroll
            for (int i = 0; i < 4; ++i) a[i] = As[kk][ty * 4 + i];
#pragma unroll
            for (int j = 0; j < 4; ++j) b[j] = Bs[kk][tx * 4 + j];
#pragma unroll
            for (int i = 0; i < 4; ++i)
#pragma unroll
                for (int j = 0; j < 4; ++j) c[i][j] += a[i] * b[j];
        }
        __syncthreads();
    }

#pragma unroll
    for (int i = 0; i < 4; ++i) {
        const int m = m0 + ty * 4 + i;
#pragma unroll
        for (int j = 0; j < 4; ++j) {
            const int n = n0 + tx * 4 + j;
            if (n < N) {
                float v = c[i][j];
                if (HAS_BIAS) v += bias[n];
                C[(size_t)m * N + n] = v;
            }
        }
    }
}

// ---------------- kv: partial over n-segments, then reduce ----------------
// part[seg][b][kc][d] = sum_{n in seg} kmat[b,n,d]*kp[n,kc]
__global__ __launch_bounds__(256)
void kv_partial(const float* __restrict__ kmat, const float* __restrict__ kp,
                float* __restrict__ part) {
    const int b = blockIdx.y;
    const int seg = blockIdx.z;
    const int kk0 = blockIdx.x * 16;
    const int tid = threadIdx.x;
    const int d = tid & 63, s = tid >> 6;

    float acc[16] = {};
    const int nbeg = seg * 512;
    for (int n = nbeg + s; n < nbeg + 512; n += 4) {
        const float kval = kmat[((size_t)b * 4096 + n) * 64 + d];
        const float* kpr = &kp[(size_t)n * 256 + kk0];
#pragma unroll
        for (int j = 0; j < 16; ++j) acc[j] += kval * kpr[j];
    }

    __shared__ float sm[16][4][64];
#pragma unroll
    for (int j = 0; j < 16; ++j) sm[j][s][d] = acc[j];
    __syncthreads();

    for (int o = tid; o < 16 * 64; o += 256) {
        const int j = o >> 6, dd = o & 63;
        part[(((size_t)seg * 4 + b) * 256 + kk0 + j) * 64 + dd] =
            sm[j][0][dd] + sm[j][1][dd] + sm[j][2][dd] + sm[j][3][dd];
    }
}

__global__ __launch_bounds__(256)
void kv_reduce(const float* __restrict__ part, float* __restrict__ kv) {
    const int i = blockIdx.x * 256 + threadIdx.x;  // over 4*256*64
    float s = 0.f;
#pragma unroll
    for (int seg = 0; seg < 8; ++seg) s += part[(size_t)seg * 4 * 256 * 64 + i];
    kv[i] = s;
}

// ---------------- attention ----------------
__global__ __launch_bounds__(64)
void attn_kernel(const float* q, const float* __restrict__ kv, float* attn) {
    const int n = blockIdx.x * 64 + threadIdx.x;
    const int h = blockIdx.y;
    const int b = blockIdx.z;
    const float* qp = q + ((size_t)(b * 4096 + n)) * 1024 + h * 64;
    const float* kvb = kv + (size_t)b * 256 * 64;

    float qv[64];
#pragma unroll
    for (int i = 0; i < 16; ++i) load4f(qp + i * 4, qv + i * 4);

    float m = -1e30f, l = 0.f;
    float acc[64];
#pragma unroll
    for (int d = 0; d < 64; ++d) acc[d] = 0.f;

    for (int k = 0; k < 256; ++k) {
        const float* kr = kvb + k * 64;
        float s = 0.f;
#pragma unroll
        for (int d = 0; d < 64; ++d) s += qv[d] * kr[d];
        s *= 0.125f;
        if (s <= m) {
            const float p = __expf(s - m);
            l += p;
#pragma unroll
            for (int d = 0; d < 64; ++d) acc[d] += p * kr[d];
        } else {
            const float corr = __expf(m - s);
            m = s;
            l = l * corr + 1.f;
#pragma unroll
            for (int d = 0; d < 64; ++d) acc[d] = acc[d] * corr + kr[d];
        }
    }

    const float inv = 1.f / l;
    float* op = attn + ((size_t)(b * 4096 + n)) * 1024 + h * 64;
#pragma unroll
    for (int d = 0; d < 64; ++d) op[d] = acc[d] * inv;
}

extern "C" void kernel_launch(void* const* d_in, const int* in_sizes, int n_in,
                              void* d_out, int out_size, void* d_ws, size_t ws_size,
                              hipStream_t stream) {
    const float* x  = (const float*)d_in[0];
    const float* qU = (const float*)d_in[1];
    const float* qV = (const float*)d_in[2];
    const float* qW = (const float*)d_in[3];
    const float* qb = (const float*)d_in[4];
    const float* kW = (const float*)d_in[5];
    const float* kp = (const float*)d_in[6];
    const float* oW = (const float*)d_in[7];
    const float* ob = (const float*)d_in[8];
    float* out = (float*)d_out;

    const int M = 4 * 4096;  // 16384
    float* ws = (float*)d_ws;
    float* t1 = ws;                                // M*32      (2 MB)
    float* t2 = t1 + (size_t)M * 32;               // M*512     (32 MB)
    float* q  = t2 + (size_t)M * 512;              // M*1024    (64 MB)
    float* km = q  + (size_t)M * 1024;             // M*64      (4 MB)
    float* kv = km + (size_t)M * 64;               // 4*256*64  (256 KB)
    float* at = q;                                 // attn out in-place
    float* part = t1;                              // reuse t1: 8*4*256*64 = 2 MB (t1 dead by kv stage)

    const dim3 blk(256);
    // 1) t1 = x @ qU^T           (M,32,K=1024)  VALU
    gemm_bt<false><<<dim3(1, M / 64), blk, 0, stream>>>(x, qU, nullptr, t1, M, 32, 1024);
    // 2) t2 = t1 @ qV^T          (M,512,K=32)   MFMA
    gemm_bt_mfma<false><<<dim3(4, M / 128), blk, 0, stream>>>(t1, qV, nullptr, t2, M, 512, 32);
    // 3) q = t2 @ qW^T + qb      (M,1024,K=512) MFMA
    gemm_bt_mfma<true><<<dim3(8, M / 128), blk, 0, stream>>>(t2, qW, qb, q, M, 1024, 512);
    // 4) k = x @ kW^T            (M,64,K=1024)  VALU
    gemm_bt<false><<<dim3(1, M / 64), blk, 0, stream>>>(x, kW, nullptr, km, M, 64, 1024);
    // 5) kv partial + reduce
    kv_partial<<<dim3(16, 4, 8), blk, 0, stream>>>(km, kp, part);
    kv_reduce<<<dim3(4 * 256 * 64 / 256), blk, 0, stream>>>(part, kv);
    // 6) attention, in-place on q
    attn_kernel<<<dim3(64, 16, 4), dim3(64), 0, stream>>>(q, kv, at);
    // 7) out = at @ oW^T + ob    (M,1024,K=1024) MFMA
    gemm_bt_mfma<true><<<dim3(8, M / 128), blk, 0, stream>>>(at, oW, ob, out, M, 1024, 1024);
}

// Round 5
// 635.020 us; speedup vs baseline: 3.1491x; 1.3621x over previous
//
#include <hip/hip_runtime.h>
#include <hip/hip_bf16.h>

// LinformerSelfAttention  B=4 N=4096 E=1024 H=16 D=64 K=256 RANK=32
// f32 I/O. All matmuls on MFMA with split-bf16 (hi/lo) operands.
// Attention fused into ONE kernel (no 128MB P buffer — round-4 bug).

typedef unsigned short u16;
typedef __attribute__((ext_vector_type(8))) short bf8;          // 8 bf16 (4 VGPR)
typedef __attribute__((ext_vector_type(4))) float f32x4;
typedef __attribute__((ext_vector_type(8))) unsigned short us8;
typedef __attribute__((ext_vector_type(4))) unsigned short us4;

__device__ __forceinline__ u16 f2bf(float x) {
    __hip_bfloat16 h = __float2bfloat16(x);
    return *reinterpret_cast<u16*>(&h);
}
__device__ __forceinline__ float bf2f16(u16 u) {
    union { unsigned int i; float f; } c; c.i = ((unsigned int)u) << 16; return c.f;
}

// ---------------- weight splitter: f32 -> (hi bf16, lo bf16) ----------------
__global__ __launch_bounds__(256)
void split_w(const float* __restrict__ src, u16* __restrict__ h,
             u16* __restrict__ l, int n4) {
    int i = blockIdx.x * 256 + threadIdx.x;
    if (i >= n4) return;
    float4 v = ((const float4*)src)[i];
    float a[4] = {v.x, v.y, v.z, v.w};
    u16 hh[4], ll[4];
#pragma unroll
    for (int e = 0; e < 4; ++e) { u16 x = f2bf(a[e]); hh[e] = x; ll[e] = f2bf(a[e] - bf2f16(x)); }
    ((us4*)h)[i] = *(const us4*)hh;
    ((us4*)l)[i] = *(const us4*)ll;
}

// ---------------- unified split-bf16 MFMA GEMM ----------------
// C[m,n] = sum_k A[m,k]*B[n,k] (+bias[n]).  BM=128, BK=32.
template <int BN, bool A_F32, bool HAS_BIAS, bool OUT_SPLIT>
__global__ __launch_bounds__(256)
void gemm_mfma(const void* __restrict__ Ah_p, const void* __restrict__ Al_p,
               const u16* __restrict__ Bh_g, const u16* __restrict__ Bl_g,
               const float* __restrict__ bias,
               void* __restrict__ Ch_p, void* __restrict__ Cl_p,
               int M, int N, int K) {
    constexpr int MI = (BN == 128) ? 4 : 2;
    constexpr int NJ = (BN == 32) ? 2 : 4;
    __shared__ u16 Ah[128][40], Al[128][40], Bh[BN][40], Bl[BN][40];
    const int t = threadIdx.x;
    const int wave = t >> 6, lane = t & 63;
    const int l15 = lane & 15, quad = lane >> 4;
    const int wm = (BN == 128) ? (wave >> 1) * 64 : wave * 32;
    const int wn = (BN == 128) ? (wave & 1) * 64 : 0;
    const int m0 = blockIdx.y * 128, n0 = blockIdx.x * BN;
    const int arow = t >> 1, acol = (t & 1) * 16;

    f32x4 acc[MI][NJ] = {};

    for (int k0 = 0; k0 < K; k0 += 32) {
        if (A_F32) {
            const float* A = (const float*)Ah_p;
            const float* src = &A[(size_t)(m0 + arow) * K + k0 + acol];
            float4 w0 = ((const float4*)src)[0], w1 = ((const float4*)src)[1];
            float4 w2 = ((const float4*)src)[2], w3 = ((const float4*)src)[3];
            float v[16] = {w0.x, w0.y, w0.z, w0.w, w1.x, w1.y, w1.z, w1.w,
                           w2.x, w2.y, w2.z, w2.w, w3.x, w3.y, w3.z, w3.w};
            u16 hh[16], ll[16];
#pragma unroll
            for (int e = 0; e < 16; ++e) {
                u16 x = f2bf(v[e]); hh[e] = x; ll[e] = f2bf(v[e] - bf2f16(x));
            }
            *(us8*)&Ah[arow][acol]     = *(const us8*)&hh[0];
            *(us8*)&Ah[arow][acol + 8] = *(const us8*)&hh[8];
            *(us8*)&Al[arow][acol]     = *(const us8*)&ll[0];
            *(us8*)&Al[arow][acol + 8] = *(const us8*)&ll[8];
        } else {
            const u16* Ag  = (const u16*)Ah_p;
            const u16* Alg = (const u16*)Al_p;
            size_t base = (size_t)(m0 + arow) * K + k0 + acol;
            *(us8*)&Ah[arow][acol]     = *(const us8*)&Ag[base];
            *(us8*)&Ah[arow][acol + 8] = *(const us8*)&Ag[base + 8];
            *(us8*)&Al[arow][acol]     = *(const us8*)&Alg[base];
            *(us8*)&Al[arow][acol + 8] = *(const us8*)&Alg[base + 8];
        }
        if (t < BN * 2) {
            const int brow = t >> 1, bcol = (t & 1) * 16;
            size_t base = (size_t)(n0 + brow) * K + k0 + bcol;
            *(us8*)&Bh[brow][bcol]     = *(const us8*)&Bh_g[base];
            *(us8*)&Bh[brow][bcol + 8] = *(const us8*)&Bh_g[base + 8];
            *(us8*)&Bl[brow][bcol]     = *(const us8*)&Bl_g[base];
            *(us8*)&Bl[brow][bcol + 8] = *(const us8*)&Bl_g[base + 8];
        }
        __syncthreads();

        bf8 ah[MI], al[MI], bh[NJ], bl[NJ];
#pragma unroll
        for (int i = 0; i < MI; ++i) {
            ah[i] = *(const bf8*)&Ah[wm + i * 16 + l15][quad * 8];
            al[i] = *(const bf8*)&Al[wm + i * 16 + l15][quad * 8];
        }
#pragma unroll
        for (int j = 0; j < NJ; ++j) {
            bh[j] = *(const bf8*)&Bh[wn + j * 16 + l15][quad * 8];
            bl[j] = *(const bf8*)&Bl[wn + j * 16 + l15][quad * 8];
        }
#pragma unroll
        for (int i = 0; i < MI; ++i)
#pragma unroll
            for (int j = 0; j < NJ; ++j) {
                acc[i][j] = __builtin_amdgcn_mfma_f32_16x16x32_bf16(ah[i], bh[j], acc[i][j], 0, 0, 0);
                acc[i][j] = __builtin_amdgcn_mfma_f32_16x16x32_bf16(ah[i], bl[j], acc[i][j], 0, 0, 0);
                acc[i][j] = __builtin_amdgcn_mfma_f32_16x16x32_bf16(al[i], bh[j], acc[i][j], 0, 0, 0);
            }
        __syncthreads();
    }

    // C/D layout: col = lane&15 (B row), row = quad*4 + reg (A row)
#pragma unroll
    for (int j = 0; j < NJ; ++j) {
        const int col = n0 + wn + j * 16 + l15;
        const float badd = HAS_BIAS ? bias[col] : 0.f;
#pragma unroll
        for (int i = 0; i < MI; ++i) {
            const int rbase = m0 + wm + i * 16 + quad * 4;
#pragma unroll
            for (int r = 0; r < 4; ++r) {
                float v = acc[i][j][r] + badd;
                size_t idx = (size_t)(rbase + r) * N + col;
                if (OUT_SPLIT) {
                    u16 hh = f2bf(v);
                    ((u16*)Ch_p)[idx] = hh;
                    ((u16*)Cl_p)[idx] = f2bf(v - bf2f16(hh));
                } else {
                    ((float*)Ch_p)[idx] = v;
                }
            }
        }
    }
}

// ---------------- kv: partial over n-segments ----------------
__global__ __launch_bounds__(256)
void kv_partial(const float* __restrict__ kmat, const float* __restrict__ kp,
                float* __restrict__ part) {
    const int b = blockIdx.y;
    const int seg = blockIdx.z;
    const int kk0 = blockIdx.x * 16;
    const int tid = threadIdx.x;
    const int d = tid & 63, s = tid >> 6;

    float acc[16] = {};
    const int nbeg = seg * 512;
    for (int n = nbeg + s; n < nbeg + 512; n += 4) {
        const float kval = kmat[((size_t)b * 4096 + n) * 64 + d];
        const float* kpr = &kp[(size_t)n * 256 + kk0];
#pragma unroll
        for (int j = 0; j < 16; ++j) acc[j] += kval * kpr[j];
    }
    __shared__ float sm[16][4][64];
#pragma unroll
    for (int j = 0; j < 16; ++j) sm[j][s][d] = acc[j];
    __syncthreads();
    for (int o = tid; o < 16 * 64; o += 256) {
        const int j = o >> 6, dd = o & 63;
        part[(((size_t)seg * 4 + b) * 256 + kk0 + j) * 64 + dd] =
            sm[j][0][dd] + sm[j][1][dd] + sm[j][2][dd] + sm[j][3][dd];
    }
}

// reduce 8 segments; emit pre-split KV ([b][k][d]) and KV^T ([b][d][k])
__global__ __launch_bounds__(256)
void kv_reduce_split(const float* __restrict__ part,
                     u16* __restrict__ kvh, u16* __restrict__ kvl,
                     u16* __restrict__ kvTh, u16* __restrict__ kvTl) {
    const int i = blockIdx.x * 256 + threadIdx.x;  // 0..65535
    float s = 0.f;
#pragma unroll
    for (int seg = 0; seg < 8; ++seg) s += part[(size_t)seg * 65536 + i];
    u16 hh = f2bf(s), ll = f2bf(s - bf2f16(hh));
    kvh[i] = hh;  kvl[i] = ll;
    const int b = i >> 14, k = (i >> 6) & 255, d = i & 63;
    size_t ti = ((size_t)b * 64 + d) * 256 + k;
    kvTh[ti] = hh;  kvTl[ti] = ll;
}

// ---------------- fused attention: scores + softmax + PV ----------------
// Block: 128 queries for one (b,h); 4 waves x 32 queries (nt=2 x 16).
// K-frags and KV^T-frags straight from global (pre-split, L2-hot).
// P converts C-layout -> A-layout through one 64 KB swizzled LDS buffer.
__global__ __launch_bounds__(256)
void attn_fused(const u16* __restrict__ qh, const u16* __restrict__ ql,
                const u16* __restrict__ kvh, const u16* __restrict__ kvl,
                const u16* __restrict__ kvTh, const u16* __restrict__ kvTl,
                u16* __restrict__ ath, u16* __restrict__ atl) {
    __shared__ u16 Ps[128][256];   // P[n_rel][k], XOR-swizzled 16B chunks
    const int b = blockIdx.z, h = blockIdx.y;
    const int t = threadIdx.x, wave = t >> 6, lane = t & 63;
    const int l15 = lane & 15, quad = lane >> 4;
    const int nblk = blockIdx.x * 128;          // global query base of block
    const int nwav = wave * 32;                 // block-relative wave base

    // Q fragments (pre-split, direct from global)
    bf8 Qh[2][2], Ql[2][2];    // [nt][c]
#pragma unroll
    for (int nt = 0; nt < 2; ++nt) {
        size_t qoff = ((size_t)(b * 4096 + nblk + nwav + nt * 16 + l15)) * 1024
                      + h * 64 + quad * 8;
#pragma unroll
        for (int c = 0; c < 2; ++c) {
            Qh[nt][c] = *(const bf8*)&qh[qoff + c * 32];
            Ql[nt][c] = *(const bf8*)&ql[qoff + c * 32];
        }
    }

    // ---- scores: S^T tiles.  A = KV rows (k), B = Q rows (n).
    f32x4 S[2][16] = {};
#pragma unroll
    for (int kt = 0; kt < 16; ++kt) {
        const int krow = kt * 16 + l15;
        size_t koff = (size_t)b * 16384 + (size_t)krow * 64 + quad * 8;
#pragma unroll
        for (int c = 0; c < 2; ++c) {
            bf8 Kh = *(const bf8*)&kvh[koff + c * 32];
            bf8 Kl = *(const bf8*)&kvl[koff + c * 32];
#pragma unroll
            for (int nt = 0; nt < 2; ++nt) {
                S[nt][kt] = __builtin_amdgcn_mfma_f32_16x16x32_bf16(Kh, Qh[nt][c], S[nt][kt], 0, 0, 0);
                S[nt][kt] = __builtin_amdgcn_mfma_f32_16x16x32_bf16(Kh, Ql[nt][c], S[nt][kt], 0, 0, 0);
                S[nt][kt] = __builtin_amdgcn_mfma_f32_16x16x32_bf16(Kl, Qh[nt][c], S[nt][kt], 0, 0, 0);
            }
        }
    }

    // ---- softmax over k for each query n = nblk+nwav+nt*16+l15.
    // Lane holds k = kt*16 + quad*4 + r; sum across quads via xor 16/32.
#pragma unroll
    for (int nt = 0; nt < 2; ++nt) {
        float sum = 0.f;
#pragma unroll
        for (int kt = 0; kt < 16; ++kt)
#pragma unroll
            for (int r = 0; r < 4; ++r) {
                float p = __expf(S[nt][kt][r] * 0.125f);
                S[nt][kt][r] = p; sum += p;
            }
        sum += __shfl_xor(sum, 16, 64);
        sum += __shfl_xor(sum, 32, 64);
        const float inv = 1.f / sum;
        const int nrel = nwav + nt * 16 + l15;
#pragma unroll
        for (int kt = 0; kt < 16; ++kt) {
            u16 pw[4];
#pragma unroll
            for (int r = 0; r < 4; ++r) pw[r] = f2bf(S[nt][kt][r] * inv);
            const int chunk16 = kt * 2 + (quad >> 1);
            const int phys = (chunk16 ^ (nrel & 7)) * 8 + (quad & 1) * 4;
            *(us4*)&Ps[nrel][phys] = *(const us4*)pw;
        }
    }
    __syncthreads();

    // ---- PV: O = P @ KV.  A = P rows (n, from LDS), B = KV^T rows (d, global).
    f32x4 O[2][4] = {};
#pragma unroll
    for (int c = 0; c < 8; ++c) {
        bf8 pf[2];
#pragma unroll
        for (int nt = 0; nt < 2; ++nt) {
            const int nrel = nwav + nt * 16 + l15;
            const int phys = (((c * 4 + quad) ^ (nrel & 7)) & 31) * 8;
            pf[nt] = *(const bf8*)&Ps[nrel][phys];
        }
#pragma unroll
        for (int dt = 0; dt < 4; ++dt) {
            const int drow = dt * 16 + l15;
            size_t toff = (size_t)b * 16384 + (size_t)drow * 256 + c * 32 + quad * 8;
            bf8 th = *(const bf8*)&kvTh[toff];
            bf8 tl = *(const bf8*)&kvTl[toff];
#pragma unroll
            for (int nt = 0; nt < 2; ++nt) {
                O[nt][dt] = __builtin_amdgcn_mfma_f32_16x16x32_bf16(pf[nt], th, O[nt][dt], 0, 0, 0);
                O[nt][dt] = __builtin_amdgcn_mfma_f32_16x16x32_bf16(pf[nt], tl, O[nt][dt], 0, 0, 0);
            }
        }
    }

    // C: col = l15 -> d, row = quad*4+r -> query.  Write pre-split.
#pragma unroll
    for (int nt = 0; nt < 2; ++nt)
#pragma unroll
        for (int dt = 0; dt < 4; ++dt) {
            const int dcol = dt * 16 + l15;
#pragma unroll
            for (int r = 0; r < 4; ++r) {
                const int query = nblk + nwav + nt * 16 + quad * 4 + r;
                float v = O[nt][dt][r];
                size_t idx = (size_t)(b * 4096 + query) * 1024 + h * 64 + dcol;
                u16 hh = f2bf(v);
                ath[idx] = hh;
                atl[idx] = f2bf(v - bf2f16(hh));
            }
        }
}

extern "C" void kernel_launch(void* const* d_in, const int* in_sizes, int n_in,
                              void* d_out, int out_size, void* d_ws, size_t ws_size,
                              hipStream_t stream) {
    const float* x  = (const float*)d_in[0];
    const float* qU = (const float*)d_in[1];
    const float* qV = (const float*)d_in[2];
    const float* qW = (const float*)d_in[3];
    const float* qb = (const float*)d_in[4];
    const float* kW = (const float*)d_in[5];
    const float* kp = (const float*)d_in[6];
    const float* oW = (const float*)d_in[7];
    const float* ob = (const float*)d_in[8];
    float* out = (float*)d_out;

    const int M = 16384;
    u16* W = (u16*)d_ws;
    u16* qUh = W;  W += 32768;    u16* qUl = W;  W += 32768;
    u16* qVh = W;  W += 16384;    u16* qVl = W;  W += 16384;
    u16* qWh = W;  W += 524288;   u16* qWl = W;  W += 524288;
    u16* kWh = W;  W += 65536;    u16* kWl = W;  W += 65536;
    u16* oWh = W;  W += 1048576;  u16* oWl = W;  W += 1048576;
    u16* t1h = W;  W += 524288;   u16* t1l = W;  W += 524288;
    u16* t2h = W;  W += 8388608;  u16* t2l = W;  W += 8388608;
    u16* qhb = W;  W += 16777216; u16* qlb = W;  W += 16777216;
    float* km  = (float*)W;  W += 2097152;     // 1048576 f32 (4 MB)
    u16* kvh  = W;  W += 65536;
    u16* kvl  = W;  W += 65536;
    u16* kvTh = W;  W += 65536;
    u16* kvTl = W;  W += 65536;
    u16* ath = qhb;                            // q dead after attn_fused reads it
    u16* atl = qlb;
    float* part = (float*)t1h;                 // 2 MB; t1 dead after step 2

    const dim3 blk(256);
    // 0) split weights
    split_w<<<dim3(32),   blk, 0, stream>>>(qU, qUh, qUl, 8192);
    split_w<<<dim3(16),   blk, 0, stream>>>(qV, qVh, qVl, 4096);
    split_w<<<dim3(512),  blk, 0, stream>>>(qW, qWh, qWl, 131072);
    split_w<<<dim3(64),   blk, 0, stream>>>(kW, kWh, kWl, 16384);
    split_w<<<dim3(1024), blk, 0, stream>>>(oW, oWh, oWl, 262144);
    // 1) t1 = x @ qU^T            (N=32, K=1024), out pre-split
    gemm_mfma<32, true, false, true><<<dim3(1, 128), blk, 0, stream>>>(
        x, nullptr, qUh, qUl, nullptr, t1h, t1l, M, 32, 1024);
    // 2) t2 = t1 @ qV^T           (N=512, K=32), out pre-split
    gemm_mfma<128, false, false, true><<<dim3(4, 128), blk, 0, stream>>>(
        t1h, t1l, qVh, qVl, nullptr, t2h, t2l, M, 512, 32);
    // 3) q = t2 @ qW^T + qb       (N=1024, K=512), out pre-split
    gemm_mfma<128, false, true, true><<<dim3(8, 128), blk, 0, stream>>>(
        t2h, t2l, qWh, qWl, qb, qhb, qlb, M, 1024, 512);
    // 4) km = x @ kW^T            (N=64, K=1024), f32 out
    gemm_mfma<64, true, false, false><<<dim3(1, 128), blk, 0, stream>>>(
        x, nullptr, kWh, kWl, nullptr, km, nullptr, M, 64, 1024);
    // 5) kv partial + reduce/split (+ transpose)
    kv_partial<<<dim3(16, 4, 8), blk, 0, stream>>>(km, kp, part);
    kv_reduce_split<<<dim3(256), blk, 0, stream>>>(part, kvh, kvl, kvTh, kvTl);
    // 6) fused attention (in-place over q buffers)
    attn_fused<<<dim3(32, 16, 4), blk, 0, stream>>>(qhb, qlb, kvh, kvl, kvTh, kvTl, ath, atl);
    // 7) out = at @ oW^T + ob     (N=1024, K=1024), f32 out
    gemm_mfma<128, false, true, false><<<dim3(8, 128), blk, 0, stream>>>(
        ath, atl, oWh, oWl, ob, out, nullptr, M, 1024, 1024);
}

// Round 6
// 605.595 us; speedup vs baseline: 3.3021x; 1.0486x over previous
//
#include <hip/hip_runtime.h>
#include <hip/hip_bf16.h>

// LinformerSelfAttention  B=4 N=4096 E=1024 H=16 D=64 K=256 RANK=32
// f32 I/O. All matmuls on MFMA with split-bf16 (hi/lo) operands.
// R6: chunked low-LDS fused attention + global_load_lds GEMM staging.

typedef unsigned short u16;
typedef __attribute__((ext_vector_type(8))) short bf8;          // 8 bf16 (4 VGPR)
typedef __attribute__((ext_vector_type(4))) float f32x4;
typedef __attribute__((ext_vector_type(8))) unsigned short us8;
typedef __attribute__((ext_vector_type(4))) unsigned short us4;

__device__ __forceinline__ u16 f2bf(float x) {
    __hip_bfloat16 h = __float2bfloat16(x);
    return *reinterpret_cast<u16*>(&h);
}
__device__ __forceinline__ float bf2f16(u16 u) {
    union { unsigned int i; float f; } c; c.i = ((unsigned int)u) << 16; return c.f;
}
__device__ __forceinline__ void async16(const void* g, void* l) {
    __builtin_amdgcn_global_load_lds(
        (const __attribute__((address_space(1))) void*)g,
        (__attribute__((address_space(3))) void*)l, 16, 0, 0);
}

// ---------------- weight splitter: f32 -> (hi bf16, lo bf16) ----------------
__global__ __launch_bounds__(256)
void split_w(const float* __restrict__ src, u16* __restrict__ h,
             u16* __restrict__ l, int n4) {
    int i = blockIdx.x * 256 + threadIdx.x;
    if (i >= n4) return;
    float4 v = ((const float4*)src)[i];
    float a[4] = {v.x, v.y, v.z, v.w};
    u16 hh[4], ll[4];
#pragma unroll
    for (int e = 0; e < 4; ++e) { u16 x = f2bf(a[e]); hh[e] = x; ll[e] = f2bf(a[e] - bf2f16(x)); }
    ((us4*)h)[i] = *(const us4*)hh;
    ((us4*)l)[i] = *(const us4*)ll;
}

// ---------------- pre-split GEMM, async LDS staging ----------------
// C[m,n] = sum_k A[m,k]*B[n,k] (+bias[n]).  BM=BN=128, BK=32.
// A,B pre-split u16. Staging via global_load_lds width=16 (m97 pattern).
template <bool HAS_BIAS, bool OUT_SPLIT>
__global__ __launch_bounds__(256)
void gemm_ps(const u16* __restrict__ Ah_g, const u16* __restrict__ Al_g,
             const u16* __restrict__ Bh_g, const u16* __restrict__ Bl_g,
             const float* __restrict__ bias,
             void* __restrict__ Ch_p, void* __restrict__ Cl_p,
             int M, int N, int K) {
    __shared__ u16 LAh[128 * 32], LAl[128 * 32], LBh[128 * 32], LBl[128 * 32];
    const int t = threadIdx.x;
    const int wave = t >> 6, lane = t & 63;
    const int l15 = lane & 15, quad = lane >> 4;
    const int wm = (wave >> 1) * 64, wn = (wave & 1) * 64;
    const int m0 = blockIdx.y * 128, n0 = blockIdx.x * 128;
    const int rl = lane >> 2, c4 = lane & 3;   // staging: row-in-16, 16B chunk

    f32x4 acc[4][4] = {};

    for (int k0 = 0; k0 < K; k0 += 32) {
#pragma unroll
        for (int j = 0; j < 2; ++j) {
            const int rloc = (wave * 2 + j) * 16 + rl;
            const size_t ga = (size_t)(m0 + rloc) * K + k0 + c4 * 8;
            const size_t gb = (size_t)(n0 + rloc) * K + k0 + c4 * 8;
            const int lo = (wave * 2 + j) * 512;   // u16 offset of this 1KB region
            async16(&Ah_g[ga], &LAh[lo]);
            async16(&Al_g[ga], &LAl[lo]);
            async16(&Bh_g[gb], &LBh[lo]);
            async16(&Bl_g[gb], &LBl[lo]);
        }
        __syncthreads();

        bf8 ah[4], al[4], bh[4], bl[4];
#pragma unroll
        for (int i = 0; i < 4; ++i) {
            ah[i] = *(const bf8*)&LAh[(wm + i * 16 + l15) * 32 + quad * 8];
            al[i] = *(const bf8*)&LAl[(wm + i * 16 + l15) * 32 + quad * 8];
            bh[i] = *(const bf8*)&LBh[(wn + i * 16 + l15) * 32 + quad * 8];
            bl[i] = *(const bf8*)&LBl[(wn + i * 16 + l15) * 32 + quad * 8];
        }
#pragma unroll
        for (int i = 0; i < 4; ++i)
#pragma unroll
            for (int j = 0; j < 4; ++j) {
                acc[i][j] = __builtin_amdgcn_mfma_f32_16x16x32_bf16(ah[i], bh[j], acc[i][j], 0, 0, 0);
                acc[i][j] = __builtin_amdgcn_mfma_f32_16x16x32_bf16(ah[i], bl[j], acc[i][j], 0, 0, 0);
                acc[i][j] = __builtin_amdgcn_mfma_f32_16x16x32_bf16(al[i], bh[j], acc[i][j], 0, 0, 0);
            }
        __syncthreads();
    }

    // C/D layout: col = lane&15 (B row), row = quad*4 + reg (A row)
#pragma unroll
    for (int j = 0; j < 4; ++j) {
        const int col = n0 + wn + j * 16 + l15;
        const float badd = HAS_BIAS ? bias[col] : 0.f;
#pragma unroll
        for (int i = 0; i < 4; ++i) {
            const int rbase = m0 + wm + i * 16 + quad * 4;
#pragma unroll
            for (int r = 0; r < 4; ++r) {
                float v = acc[i][j][r] + badd;
                size_t idx = (size_t)(rbase + r) * N + col;
                if (OUT_SPLIT) {
                    u16 hh = f2bf(v);
                    ((u16*)Ch_p)[idx] = hh;
                    ((u16*)Cl_p)[idx] = f2bf(v - bf2f16(hh));
                } else {
                    ((float*)Ch_p)[idx] = v;
                }
            }
        }
    }
}

// ---------------- f32-A GEMM (steps 1,4: A = x, small N) ----------------
template <int BN, bool OUT_SPLIT>
__global__ __launch_bounds__(256)
void gemm_xa(const float* __restrict__ A,
             const u16* __restrict__ Bh_g, const u16* __restrict__ Bl_g,
             void* __restrict__ Ch_p, void* __restrict__ Cl_p,
             int M, int N, int K) {
    constexpr int MI = (BN == 128) ? 4 : 2;
    constexpr int NJ = (BN == 32) ? 2 : 4;
    __shared__ u16 Ah[128][40], Al[128][40], Bh[BN][40], Bl[BN][40];
    const int t = threadIdx.x;
    const int wave = t >> 6, lane = t & 63;
    const int l15 = lane & 15, quad = lane >> 4;
    const int wm = (BN == 128) ? (wave >> 1) * 64 : wave * 32;
    const int wn = (BN == 128) ? (wave & 1) * 64 : 0;
    const int m0 = blockIdx.y * 128, n0 = blockIdx.x * BN;
    const int arow = t >> 1, acol = (t & 1) * 16;

    f32x4 acc[MI][NJ] = {};

    for (int k0 = 0; k0 < K; k0 += 32) {
        {
            const float* src = &A[(size_t)(m0 + arow) * K + k0 + acol];
            float4 w0 = ((const float4*)src)[0], w1 = ((const float4*)src)[1];
            float4 w2 = ((const float4*)src)[2], w3 = ((const float4*)src)[3];
            float v[16] = {w0.x, w0.y, w0.z, w0.w, w1.x, w1.y, w1.z, w1.w,
                           w2.x, w2.y, w2.z, w2.w, w3.x, w3.y, w3.z, w3.w};
            u16 hh[16], ll[16];
#pragma unroll
            for (int e = 0; e < 16; ++e) {
                u16 x = f2bf(v[e]); hh[e] = x; ll[e] = f2bf(v[e] - bf2f16(x));
            }
            *(us8*)&Ah[arow][acol]     = *(const us8*)&hh[0];
            *(us8*)&Ah[arow][acol + 8] = *(const us8*)&hh[8];
            *(us8*)&Al[arow][acol]     = *(const us8*)&ll[0];
            *(us8*)&Al[arow][acol + 8] = *(const us8*)&ll[8];
        }
        if (t < BN * 2) {
            const int brow = t >> 1, bcol = (t & 1) * 16;
            size_t base = (size_t)(n0 + brow) * K + k0 + bcol;
            *(us8*)&Bh[brow][bcol]     = *(const us8*)&Bh_g[base];
            *(us8*)&Bh[brow][bcol + 8] = *(const us8*)&Bh_g[base + 8];
            *(us8*)&Bl[brow][bcol]     = *(const us8*)&Bl_g[base];
            *(us8*)&Bl[brow][bcol + 8] = *(const us8*)&Bl_g[base + 8];
        }
        __syncthreads();

        bf8 ah[MI], al[MI], bh[NJ], bl[NJ];
#pragma unroll
        for (int i = 0; i < MI; ++i) {
            ah[i] = *(const bf8*)&Ah[wm + i * 16 + l15][quad * 8];
            al[i] = *(const bf8*)&Al[wm + i * 16 + l15][quad * 8];
        }
#pragma unroll
        for (int j = 0; j < NJ; ++j) {
            bh[j] = *(const bf8*)&Bh[wn + j * 16 + l15][quad * 8];
            bl[j] = *(const bf8*)&Bl[wn + j * 16 + l15][quad * 8];
        }
#pragma unroll
        for (int i = 0; i < MI; ++i)
#pragma unroll
            for (int j = 0; j < NJ; ++j) {
                acc[i][j] = __builtin_amdgcn_mfma_f32_16x16x32_bf16(ah[i], bh[j], acc[i][j], 0, 0, 0);
                acc[i][j] = __builtin_amdgcn_mfma_f32_16x16x32_bf16(ah[i], bl[j], acc[i][j], 0, 0, 0);
                acc[i][j] = __builtin_amdgcn_mfma_f32_16x16x32_bf16(al[i], bh[j], acc[i][j], 0, 0, 0);
            }
        __syncthreads();
    }

#pragma unroll
    for (int j = 0; j < NJ; ++j) {
        const int col = n0 + wn + j * 16 + l15;
#pragma unroll
        for (int i = 0; i < MI; ++i) {
            const int rbase = m0 + wm + i * 16 + quad * 4;
#pragma unroll
            for (int r = 0; r < 4; ++r) {
                float v = acc[i][j][r];
                size_t idx = (size_t)(rbase + r) * N + col;
                if (OUT_SPLIT) {
                    u16 hh = f2bf(v);
                    ((u16*)Ch_p)[idx] = hh;
                    ((u16*)Cl_p)[idx] = f2bf(v - bf2f16(hh));
                } else {
                    ((float*)Ch_p)[idx] = v;
                }
            }
        }
    }
}

// ---------------- kv: partial over n-segments ----------------
__global__ __launch_bounds__(256)
void kv_partial(const float* __restrict__ kmat, const float* __restrict__ kp,
                float* __restrict__ part) {
    const int b = blockIdx.y;
    const int seg = blockIdx.z;
    const int kk0 = blockIdx.x * 16;
    const int tid = threadIdx.x;
    const int d = tid & 63, s = tid >> 6;

    float acc[16] = {};
    const int nbeg = seg * 512;
    for (int n = nbeg + s; n < nbeg + 512; n += 4) {
        const float kval = kmat[((size_t)b * 4096 + n) * 64 + d];
        const float* kpr = &kp[(size_t)n * 256 + kk0];
#pragma unroll
        for (int j = 0; j < 16; ++j) acc[j] += kval * kpr[j];
    }
    __shared__ float sm[16][4][64];
#pragma unroll
    for (int j = 0; j < 16; ++j) sm[j][s][d] = acc[j];
    __syncthreads();
    for (int o = tid; o < 16 * 64; o += 256) {
        const int j = o >> 6, dd = o & 63;
        part[(((size_t)seg * 4 + b) * 256 + kk0 + j) * 64 + dd] =
            sm[j][0][dd] + sm[j][1][dd] + sm[j][2][dd] + sm[j][3][dd];
    }
}

// reduce 8 segments; emit pre-split KV ([b][k][d]) and KV^T ([b][d][k])
__global__ __launch_bounds__(256)
void kv_reduce_split(const float* __restrict__ part,
                     u16* __restrict__ kvh, u16* __restrict__ kvl,
                     u16* __restrict__ kvTh, u16* __restrict__ kvTl) {
    const int i = blockIdx.x * 256 + threadIdx.x;  // 0..65535
    float s = 0.f;
#pragma unroll
    for (int seg = 0; seg < 8; ++seg) s += part[(size_t)seg * 65536 + i];
    u16 hh = f2bf(s), ll = f2bf(s - bf2f16(hh));
    kvh[i] = hh;  kvl[i] = ll;
    const int b = i >> 14, k = (i >> 6) & 255, d = i & 63;
    size_t ti = ((size_t)b * 64 + d) * 256 + k;
    kvTh[ti] = hh;  kvTl[ti] = ll;
}

// ---------------- fused attention v2: chunked, low-LDS ----------------
// Block: 128 queries x one (b,h); 4 waves x 32 queries. 4 chunks of 64 keys.
// Unnormalized exp(P) -> 18KB LDS -> PV; divide O by reduced sum at end.
__global__ __launch_bounds__(256)
void attn_fused(const u16* __restrict__ qh, const u16* __restrict__ ql,
                const u16* __restrict__ kvh, const u16* __restrict__ kvl,
                const u16* __restrict__ kvTh, const u16* __restrict__ kvTl,
                u16* __restrict__ ath, u16* __restrict__ atl) {
    __shared__ u16 Ps[128][72];    // chunk of P[n_rel][k_loc], stride 72 u16
    const int b = blockIdx.z, h = blockIdx.y;
    const int t = threadIdx.x, wave = t >> 6, lane = t & 63;
    const int l15 = lane & 15, quad = lane >> 4;
    const int nblk = blockIdx.x * 128;
    const int nwav = wave * 32;

    // Q fragments (pre-split, direct from global)
    bf8 Qh[2][2], Ql[2][2];
#pragma unroll
    for (int nt = 0; nt < 2; ++nt) {
        size_t qoff = ((size_t)(b * 4096 + nblk + nwav + nt * 16 + l15)) * 1024
                      + h * 64 + quad * 8;
#pragma unroll
        for (int c = 0; c < 2; ++c) {
            Qh[nt][c] = *(const bf8*)&qh[qoff + c * 32];
            Ql[nt][c] = *(const bf8*)&ql[qoff + c * 32];
        }
    }

    f32x4 O[2][4] = {};
    float rsum[2] = {0.f, 0.f};

    for (int kc = 0; kc < 4; ++kc) {
        // ---- scores for this 64-key chunk
        f32x4 S[2][4] = {};
#pragma unroll
        for (int ktl = 0; ktl < 4; ++ktl) {
            const int krow = kc * 64 + ktl * 16 + l15;
            size_t koff = (size_t)b * 16384 + (size_t)krow * 64 + quad * 8;
#pragma unroll
            for (int c = 0; c < 2; ++c) {
                bf8 Kh = *(const bf8*)&kvh[koff + c * 32];
                bf8 Kl = *(const bf8*)&kvl[koff + c * 32];
#pragma unroll
                for (int nt = 0; nt < 2; ++nt) {
                    S[nt][ktl] = __builtin_amdgcn_mfma_f32_16x16x32_bf16(Kh, Qh[nt][c], S[nt][ktl], 0, 0, 0);
                    S[nt][ktl] = __builtin_amdgcn_mfma_f32_16x16x32_bf16(Kh, Ql[nt][c], S[nt][ktl], 0, 0, 0);
                    S[nt][ktl] = __builtin_amdgcn_mfma_f32_16x16x32_bf16(Kl, Qh[nt][c], S[nt][ktl], 0, 0, 0);
                }
            }
        }
        // ---- exp (no max-sub; s is O(1)), unnormalized bf16 P to LDS
#pragma unroll
        for (int nt = 0; nt < 2; ++nt) {
            const int nrel = nwav + nt * 16 + l15;
#pragma unroll
            for (int ktl = 0; ktl < 4; ++ktl) {
                u16 pw[4];
#pragma unroll
                for (int r = 0; r < 4; ++r) {
                    float p = __expf(S[nt][ktl][r] * 0.125f);
                    rsum[nt] += p;
                    pw[r] = f2bf(p);
                }
                *(us4*)&Ps[nrel][ktl * 16 + quad * 4] = *(const us4*)pw;
            }
        }
        __syncthreads();

        // ---- PV for this chunk
#pragma unroll
        for (int c = 0; c < 2; ++c) {
            bf8 pf[2];
#pragma unroll
            for (int nt = 0; nt < 2; ++nt) {
                const int nrel = nwav + nt * 16 + l15;
                pf[nt] = *(const bf8*)&Ps[nrel][c * 32 + quad * 8];
            }
#pragma unroll
            for (int dt = 0; dt < 4; ++dt) {
                const int drow = dt * 16 + l15;
                size_t toff = (size_t)b * 16384 + (size_t)drow * 256
                              + kc * 64 + c * 32 + quad * 8;
                bf8 th = *(const bf8*)&kvTh[toff];
                bf8 tl = *(const bf8*)&kvTl[toff];
#pragma unroll
                for (int nt = 0; nt < 2; ++nt) {
                    O[nt][dt] = __builtin_amdgcn_mfma_f32_16x16x32_bf16(pf[nt], th, O[nt][dt], 0, 0, 0);
                    O[nt][dt] = __builtin_amdgcn_mfma_f32_16x16x32_bf16(pf[nt], tl, O[nt][dt], 0, 0, 0);
                }
            }
        }
        __syncthreads();
    }

    // full softmax denominators (per query n = nwav+nt*16+l15)
    float inv[2];
#pragma unroll
    for (int nt = 0; nt < 2; ++nt) {
        float s = rsum[nt];
        s += __shfl_xor(s, 16, 64);
        s += __shfl_xor(s, 32, 64);
        inv[nt] = 1.f / s;
    }

    // C: col = l15 -> d, row = quad*4+r -> query. Fetch that query's inv via
    // shfl(width=16): source lane has l15 == quad*4+r, same quad group.
#pragma unroll
    for (int nt = 0; nt < 2; ++nt)
#pragma unroll
        for (int dt = 0; dt < 4; ++dt) {
            const int dcol = dt * 16 + l15;
#pragma unroll
            for (int r = 0; r < 4; ++r) {
                const float qinv = __shfl(inv[nt], quad * 4 + r, 16);
                const int query = nblk + nwav + nt * 16 + quad * 4 + r;
                float v = O[nt][dt][r] * qinv;
                size_t idx = (size_t)(b * 4096 + query) * 1024 + h * 64 + dcol;
                u16 hh = f2bf(v);
                ath[idx] = hh;
                atl[idx] = f2bf(v - bf2f16(hh));
            }
        }
}

extern "C" void kernel_launch(void* const* d_in, const int* in_sizes, int n_in,
                              void* d_out, int out_size, void* d_ws, size_t ws_size,
                              hipStream_t stream) {
    const float* x  = (const float*)d_in[0];
    const float* qU = (const float*)d_in[1];
    const float* qV = (const float*)d_in[2];
    const float* qW = (const float*)d_in[3];
    const float* qb = (const float*)d_in[4];
    const float* kW = (const float*)d_in[5];
    const float* kp = (const float*)d_in[6];
    const float* oW = (const float*)d_in[7];
    const float* ob = (const float*)d_in[8];
    float* out = (float*)d_out;

    const int M = 16384;
    u16* W = (u16*)d_ws;
    u16* qUh = W;  W += 32768;    u16* qUl = W;  W += 32768;
    u16* qVh = W;  W += 16384;    u16* qVl = W;  W += 16384;
    u16* qWh = W;  W += 524288;   u16* qWl = W;  W += 524288;
    u16* kWh = W;  W += 65536;    u16* kWl = W;  W += 65536;
    u16* oWh = W;  W += 1048576;  u16* oWl = W;  W += 1048576;
    u16* t1h = W;  W += 524288;   u16* t1l = W;  W += 524288;
    u16* t2h = W;  W += 8388608;  u16* t2l = W;  W += 8388608;
    u16* qhb = W;  W += 16777216; u16* qlb = W;  W += 16777216;
    float* km  = (float*)W;  W += 2097152;     // 1048576 f32 (4 MB)
    u16* kvh  = W;  W += 65536;
    u16* kvl  = W;  W += 65536;
    u16* kvTh = W;  W += 65536;
    u16* kvTl = W;  W += 65536;
    u16* ath = qhb;                            // in-place over q buffers
    u16* atl = qlb;
    float* part = (float*)t1h;                 // 2 MB; t1 dead after step 2

    const dim3 blk(256);
    // 0) split weights
    split_w<<<dim3(32),   blk, 0, stream>>>(qU, qUh, qUl, 8192);
    split_w<<<dim3(16),   blk, 0, stream>>>(qV, qVh, qVl, 4096);
    split_w<<<dim3(512),  blk, 0, stream>>>(qW, qWh, qWl, 131072);
    split_w<<<dim3(64),   blk, 0, stream>>>(kW, kWh, kWl, 16384);
    split_w<<<dim3(1024), blk, 0, stream>>>(oW, oWh, oWl, 262144);
    // 1) t1 = x @ qU^T            (N=32, K=1024), out pre-split
    gemm_xa<32, true><<<dim3(1, 128), blk, 0, stream>>>(
        x, qUh, qUl, t1h, t1l, M, 32, 1024);
    // 2) t2 = t1 @ qV^T           (N=512, K=32), out pre-split
    gemm_ps<false, true><<<dim3(4, 128), blk, 0, stream>>>(
        t1h, t1l, qVh, qVl, nullptr, t2h, t2l, M, 512, 32);
    // 3) q = t2 @ qW^T + qb       (N=1024, K=512), out pre-split
    gemm_ps<true, true><<<dim3(8, 128), blk, 0, stream>>>(
        t2h, t2l, qWh, qWl, qb, qhb, qlb, M, 1024, 512);
    // 4) km = x @ kW^T            (N=64, K=1024), f32 out
    gemm_xa<64, false><<<dim3(1, 128), blk, 0, stream>>>(
        x, kWh, kWl, km, nullptr, M, 64, 1024);
    // 5) kv partial + reduce/split (+ transpose)
    kv_partial<<<dim3(16, 4, 8), blk, 0, stream>>>(km, kp, part);
    kv_reduce_split<<<dim3(256), blk, 0, stream>>>(part, kvh, kvl, kvTh, kvTl);
    // 6) fused attention (in-place over q buffers)
    attn_fused<<<dim3(32, 16, 4), blk, 0, stream>>>(qhb, qlb, kvh, kvl, kvTh, kvTl, ath, atl);
    // 7) out = at @ oW^T + ob     (N=1024, K=1024), f32 out
    gemm_ps<true, false><<<dim3(8, 128), blk, 0, stream>>>(
        ath, atl, oWh, oWl, ob, out, nullptr, M, 1024, 1024);
}